// Round 6
// baseline (480.971 us; speedup 1.0000x reference)
//
#include <hip/hip_runtime.h>
#include <stdint.h>

#define M_DIM 8192
#define K_DIM 4096
#define O_DIM 4096
#define NWORDS 128

typedef __attribute__((ext_vector_type(8))) short bf16x8;
typedef __attribute__((ext_vector_type(4))) float f32x4;
typedef __attribute__((ext_vector_type(4))) float fvec4;
typedef __attribute__((ext_vector_type(4))) unsigned uvec4;

__device__ __forceinline__ unsigned f32_to_bf16u(float f) {
  union { float f; unsigned u; } v; v.f = f;
  return (v.u + 0x7FFFu + ((v.u >> 16) & 1u)) >> 16;   // round-to-nearest-even
}

__device__ __forceinline__ unsigned pack_bf16x2(float lo, float hi) {
  return f32_to_bf16u(lo) | (f32_to_bf16u(hi) << 16);
}

// ---- phase 1a: x fp32->bf16 (grid-stride, 16 B stores) ----------------------
// Idempotent: launched twice this round as a timing diagnostic (2nd launch
// re-writes identical data; dur_us delta vs R4 == real prep cost).
__global__ __launch_bounds__(256) void cvt_kernel(const fvec4* __restrict__ x,
                                                  uvec4* __restrict__ xb4) {
  const int b   = blockIdx.x;
  const int tid = threadIdx.x;
  for (long p = (long)b * 256 + tid; p < 4194304; p += 524288) {
    const fvec4 v0 = x[2 * p];
    const fvec4 v1 = x[2 * p + 1];
    uvec4 o;
    o.x = pack_bf16x2(v0.x, v0.y);
    o.y = pack_bf16x2(v0.z, v0.w);
    o.z = pack_bf16x2(v1.x, v1.y);
    o.w = pack_bf16x2(v1.z, v1.w);
    xb4[p] = o;
  }
}

// ---- phase 1b: ternary unpack -> bf16 (grid-stride, 16 B stores) ------------
__global__ __launch_bounds__(256) void unpack_kernel(const unsigned* __restrict__ nz,
                                                     const unsigned* __restrict__ sgn,
                                                     unsigned short* __restrict__ wb) {
  const int b   = blockIdx.x;
  const int tid = threadIdx.x;
  for (long i = (long)b * 256 + tid; i < 2097152; i += 131072) {
    const int w = (int)(i >> 2);
    const int q = (int)(i & 3);
    const unsigned n = nz[w] >> (8 * q);
    const unsigned s = sgn[w] >> (8 * q);
    unsigned out[4];
#pragma unroll
    for (int pq = 0; pq < 4; ++pq) {
      const int j0 = 2 * pq, j1 = 2 * pq + 1;
      unsigned lo = ((n >> j0) & 1u) ? (0x3F80u | (((s >> j0) & 1u) << 15)) : 0u;
      unsigned hi = ((n >> j1) & 1u) ? (0x3F80u | (((s >> j1) & 1u) << 15)) : 0u;
      out[pq] = lo | (hi << 16);
    }
    uvec4 v = { out[0], out[1], out[2], out[3] };
    *(uvec4*)(wb + (long)w * 32 + q * 8) = v;
  }
}

// ---- phase 2: bf16 GEMM, 256x256 tile, BK=64, 8-wave, 8-phase pipeline v2 ---
// REVERTED verbatim to the R4 kernel (best verified: 237.6 us, MfmaUtil 51.4,
// SQ_LDS_BANK_CONFLICT 0). The R5 32x32 experiment regressed (conflicts 2.5e7,
// MfmaUtil 45) -- 16x16x32 with this swizzle is the verified-fast shape.
// Reads 12/4/4/4 b128/phase; stages 1 half-tile/phase; vmcnt(4) at p4/p8.
__global__ __launch_bounds__(512, 2) void gemm_kernel(const unsigned short* __restrict__ A,
                                                      const unsigned short* __restrict__ B,
                                                      const float* __restrict__ bias,
                                                      const float* __restrict__ alpha,
                                                      float* __restrict__ C) {
  __shared__ unsigned short lds[65536];   // 128 KiB: A [buf][half] then B

  const int tid  = threadIdx.x;
  const int lane = tid & 63;
  const int wave = tid >> 6;        // 8 waves: 2(M) x 4(N)
  const int wm   = wave >> 2;       // M offset wm*128
  const int wn   = wave & 3;        // N offset wn*64

  // XCD-aware bijective swizzle (nwg = 512, divisible by 8)
  const int wg   = blockIdx.x;
  const int swz  = (wg & 7) * 64 + (wg >> 3);
  const int nBlk = (swz & 15) * 256;
  const int mBlk = (swz >> 4) * 256;

  const unsigned short* Apan = A + (long)mBlk * K_DIM;
  const unsigned short* Bpan = B + (long)nBlk * K_DIM;

  // staging map: half-tile = 128x64 bf16 = 16 KiB = 1024 chunks of 16 B.
  // LDS dest linear (m104); SOURCE carries the inverse swizzle (rule 21).
  int lOff[2], gOff[2];
#pragma unroll
  for (int l = 0; l < 2; ++l) {
    const int o = (l * 512 + tid) * 16;           // LDS byte offset in half slot
    const int r = o >> 7;                         // row (128 B per row)
    const int q = ((o >> 4) & 7) ^ (r & 7);       // global chunk (inverse swz)
    lOff[l] = o;
    gOff[l] = r * K_DIM + q * 8;                  // shorts
  }

  // fragment addressing (verified lane mapping)
  const int fr  = lane & 15;                      // row within 16-frag
  const int fq  = lane >> 4;                      // k-quad
  const int sl0 = fq ^ (fr & 7);                  // chunk slot kh=0 (kh=1: ^4)
  const int aFB = fr * 64;                        // shorts
  const int bFB = (wn & 1) * 4096 + fr * 64;
  const int A0S = wm * 8192;                      // A buf0, half wm
  const int A1S = (2 + wm) * 8192;                // A buf1, half wm
  const int B0S = 32768 + (wn >> 1) * 8192;       // B buf0, half wn>>1
  const int B1S = 32768 + (2 + (wn >> 1)) * 8192; // B buf1, half wn>>1

  f32x4  acc[8][4] = {};
  bf16x8 a[2][2], bv[4][2];

#define STAGE(SUBv, BUFv, TILEv) do {                                          \
    const unsigned short* s_ = (((SUBv) < 2) ? Apan : Bpan)                    \
        + (long)((SUBv) & 1) * (128 * K_DIM) + (long)(TILEv) * 64;             \
    const int dB = ((((SUBv) < 2) ? 0 : 32768)                                 \
        + (((BUFv) * 2) + ((SUBv) & 1)) * 8192) * 2;                           \
    __builtin_amdgcn_global_load_lds(                                          \
        (const __attribute__((address_space(1))) void*)(s_ + gOff[0]),         \
        (__attribute__((address_space(3))) void*)((char*)lds + dB + lOff[0]),  \
        16, 0, 0);                                                             \
    __builtin_amdgcn_global_load_lds(                                          \
        (const __attribute__((address_space(1))) void*)(s_ + gOff[1]),         \
        (__attribute__((address_space(3))) void*)((char*)lds + dB + lOff[1]),  \
        16, 0, 0);                                                             \
  } while (0)

// a-frags for M-row-pair P (rows 32P..32P+31 of wave's A-half): 4 ds_read_b128
#define LOADA2(BASE, P)                                                        \
  _Pragma("unroll")                                                            \
  for (int i = 0; i < 2; ++i) {                                                \
    const int off_ = (BASE) + ((P) * 2 + i) * 1024 + aFB;                      \
    a[i][0] = *(const bf16x8*)(lds + off_ + sl0 * 8);                          \
    a[i][1] = *(const bf16x8*)(lds + off_ + (sl0 ^ 4) * 8);                    \
  }

// all 4 B frags of wave's half: 8 ds_read_b128 (only at p1/p5)
#define LOADB(BASE)                                                            \
  _Pragma("unroll")                                                            \
  for (int j = 0; j < 4; ++j) {                                                \
    const int off_ = (BASE) + bFB + j * 1024;                                  \
    bv[j][0] = *(const bf16x8*)(lds + off_ + sl0 * 8);                         \
    bv[j][1] = *(const bf16x8*)(lds + off_ + (sl0 ^ 4) * 8);                   \
  }

// 16 MFMA: M-row-pair P x all 4 N x both kh
#define MFMA2(P)                                                               \
  _Pragma("unroll")                                                            \
  for (int kh = 0; kh < 2; ++kh)                                               \
    _Pragma("unroll")                                                          \
    for (int i = 0; i < 2; ++i)                                                \
      _Pragma("unroll")                                                        \
      for (int tn = 0; tn < 4; ++tn)                                           \
        acc[(P) * 2 + i][tn] = __builtin_amdgcn_mfma_f32_16x16x32_bf16(        \
            a[i][kh], bv[tn][kh], acc[(P) * 2 + i][tn], 0, 0, 0);

#define PRE12()   asm volatile("s_waitcnt lgkmcnt(8)" ::: "memory")
#define MID()  __builtin_amdgcn_s_barrier();                                   \
               asm volatile("s_waitcnt lgkmcnt(0)" ::: "memory");              \
               __builtin_amdgcn_s_setprio(1)
#define ENDPH()   __builtin_amdgcn_s_setprio(0); __builtin_amdgcn_s_barrier()
#define ENDVM4()  __builtin_amdgcn_s_setprio(0);                               \
                  asm volatile("s_waitcnt vmcnt(4)" ::: "memory");             \
                  __builtin_amdgcn_s_barrier()
#define ENDVM0()  __builtin_amdgcn_s_setprio(0);                               \
                  asm volatile("s_waitcnt vmcnt(0)" ::: "memory");             \
                  __builtin_amdgcn_s_barrier()

  // ---- prologue: tile0 {B0,B1,A0,A1} + tile1 {B0,B1} ----
  STAGE(2, 0, 0); STAGE(3, 0, 0); STAGE(0, 0, 0); STAGE(1, 0, 0);
  STAGE(2, 1, 1); STAGE(3, 1, 1);
  asm volatile("s_waitcnt vmcnt(4)" ::: "memory");   // tile 0 fully landed
  __builtin_amdgcn_s_barrier();

  // ---- main loop: 31 iterations, computing tiles 0..61 ----
  for (int it = 0; it < (K_DIM / 64) / 2 - 1; ++it) {
    const int t1 = 2 * it + 1, t2 = 2 * it + 2, t3 = 2 * it + 3;
    // p1..p4: tile 2it (buf0)
    LOADA2(A0S, 0); LOADB(B0S); STAGE(1, 1, t1); PRE12();
                                                 MID(); MFMA2(0); ENDPH();
    LOADA2(A0S, 1);             STAGE(0, 1, t1); MID(); MFMA2(1); ENDPH();
    LOADA2(A0S, 2);             STAGE(2, 0, t2); MID(); MFMA2(2); ENDPH();
    LOADA2(A0S, 3);             STAGE(3, 0, t2); MID(); MFMA2(3); ENDVM4();
    // p5..p8: tile 2it+1 (buf1)
    LOADA2(A1S, 0); LOADB(B1S); STAGE(0, 0, t2); PRE12();
                                                 MID(); MFMA2(0); ENDPH();
    LOADA2(A1S, 1);             STAGE(1, 0, t2); MID(); MFMA2(1); ENDPH();
    LOADA2(A1S, 2);             STAGE(2, 1, t3); MID(); MFMA2(2); ENDPH();
    LOADA2(A1S, 3);             STAGE(3, 1, t3); MID(); MFMA2(3); ENDVM4();
  }

  // ---- epilogue: tile 62 (buf0) + tile 63 (buf1); A1(63),A0(63) to stage ----
  LOADA2(A0S, 0); LOADB(B0S); STAGE(1, 1, 63); PRE12();
                                               MID(); MFMA2(0); ENDPH();
  LOADA2(A0S, 1);             STAGE(0, 1, 63); MID(); MFMA2(1); ENDPH();
  LOADA2(A0S, 2);                              MID(); MFMA2(2); ENDPH();
  LOADA2(A0S, 3);                              MID(); MFMA2(3); ENDVM0();
  LOADA2(A1S, 0); LOADB(B1S);                  MID(); MFMA2(0); ENDPH();
  LOADA2(A1S, 1);                              MID(); MFMA2(1); ENDPH();
  LOADA2(A1S, 2);                              MID(); MFMA2(2); ENDPH();
  LOADA2(A1S, 3);                              MID(); MFMA2(3);
  __builtin_amdgcn_s_setprio(0);

  // ---- C write: C[m][n] = acc * alpha[n] + bias[n] (nontemporal, write-once)
  // C/D layout (verified m89/m91): col = lane&15, row = (lane>>4)*4 + reg
#pragma unroll
  for (int tn = 0; tn < 4; ++tn) {
    const int n = nBlk + wn * 64 + tn * 16 + fr;
    const float al = alpha[n];
    const float bi = bias[n];
#pragma unroll
    for (int tm = 0; tm < 8; ++tm) {
      const int mBase = mBlk + wm * 128 + tm * 16 + fq * 4;
#pragma unroll
      for (int r = 0; r < 4; ++r)
        __builtin_nontemporal_store(acc[tm][tn][r] * al + bi,
                                    C + (long)(mBase + r) * O_DIM + n);
    }
  }

#undef STAGE
#undef LOADA2
#undef LOADB
#undef MFMA2
#undef PRE12
#undef MID
#undef ENDPH
#undef ENDVM4
#undef ENDVM0
}

// ---- fallback (ws too small): slow but correct fp32 path --------------------
__global__ __launch_bounds__(256) void fallback_kernel(const float* __restrict__ x,
                                                       const unsigned* __restrict__ nz,
                                                       const unsigned* __restrict__ sgn,
                                                       const float* __restrict__ bias,
                                                       const float* __restrict__ alpha,
                                                       float* __restrict__ y) {
  long gid = (long)blockIdx.x * 256 + threadIdx.x;
  int o = (int)(gid % O_DIM);
  long m = gid / O_DIM;
  const float* xr = x + m * K_DIM;
  float s = 0.f;
  for (int w = 0; w < NWORDS; ++w) {
    unsigned n = nz[o * NWORDS + w];
    unsigned g = sgn[o * NWORDS + w];
    for (int j = 0; j < 32; ++j) {
      if ((n >> j) & 1u) {
        float v = xr[w * 32 + j];
        s += ((g >> j) & 1u) ? -v : v;
      }
    }
  }
  y[gid] = s * alpha[o] + bias[o];
}

extern "C" void kernel_launch(void* const* d_in, const int* in_sizes, int n_in,
                              void* d_out, int out_size, void* d_ws, size_t ws_size,
                              hipStream_t stream) {
  const float*    x     = (const float*)d_in[0];
  const unsigned* nz    = (const unsigned*)d_in[1];
  const unsigned* sgn   = (const unsigned*)d_in[2];
  const float*    bias  = (const float*)d_in[3];
  const float*    alpha = (const float*)d_in[4];
  float*          y     = (float*)d_out;

  const size_t xb_bytes = (size_t)M_DIM * K_DIM * 2;   // 64 MiB
  const size_t wb_bytes = (size_t)O_DIM * K_DIM * 2;   // 32 MiB

  if (ws_size >= xb_bytes + wb_bytes) {
    unsigned short* xb = (unsigned short*)d_ws;
    unsigned short* wb = (unsigned short*)((char*)d_ws + xb_bytes);

    // DIAGNOSTIC (this round): each prep kernel launched TWICE (idempotent).
    // dur_us - 237(gemm) - X_fixed reveals the real prep cost:
    // total ~625 us -> prep is ~190 us of real work (fuse it next round);
    // total ~480 us -> prep is ~45 us and ~155 us is fixed harness overhead.
    cvt_kernel<<<2048, 256, 0, stream>>>((const fvec4*)x, (uvec4*)xb);
    cvt_kernel<<<2048, 256, 0, stream>>>((const fvec4*)x, (uvec4*)xb);
    unpack_kernel<<<512, 256, 0, stream>>>(nz, sgn, wb);
    unpack_kernel<<<512, 256, 0, stream>>>(nz, sgn, wb);
    gemm_kernel<<<512, 512, 0, stream>>>(xb, wb, bias, alpha, y);
  } else {
    fallback_kernel<<<(long)M_DIM * O_DIM / 256, 256, 0, stream>>>(x, nz, sgn, bias, alpha, y);
  }
}

// Round 8
// 429.432 us; speedup vs baseline: 1.1200x; 1.1200x over previous
//
#include <hip/hip_runtime.h>
#include <stdint.h>

#define M_DIM 8192
#define K_DIM 4096
#define O_DIM 4096
#define NWORDS 128

typedef __attribute__((ext_vector_type(8))) short bf16x8;
typedef __attribute__((ext_vector_type(4))) float f32x4;
typedef __attribute__((ext_vector_type(4))) float fvec4;
typedef __attribute__((ext_vector_type(4))) unsigned uvec4;

__device__ __forceinline__ unsigned f32_to_bf16u(float f) {
  union { float f; unsigned u; } v; v.f = f;
  return (v.u + 0x7FFFu + ((v.u >> 16) & 1u)) >> 16;   // round-to-nearest-even
}

__device__ __forceinline__ unsigned pack_bf16x2(float lo, float hi) {
  return f32_to_bf16u(lo) | (f32_to_bf16u(hi) << 16);
}

// ---- phase 1: x fp32->bf16 AND ternary unpack (R4 measured-best config) -----
// R6 diagnostic: one full prep pass = 45.7 us (~78% of its traffic roofline);
// total-gemm-prep ~152 us is fixed harness overhead. Prep is done.
__global__ __launch_bounds__(256) void prep_kernel(const fvec4* __restrict__ x,
                                                   uvec4* __restrict__ xb4,
                                                   const unsigned* __restrict__ nz,
                                                   const unsigned* __restrict__ sgn,
                                                   unsigned short* __restrict__ wb) {
  const int b   = blockIdx.x;
  const int tid = threadIdx.x;
  if (b < 2048) {
    for (long p = (long)b * 256 + tid; p < 4194304; p += 524288) {
      const fvec4 v0 = x[2 * p];
      const fvec4 v1 = x[2 * p + 1];
      uvec4 o;
      o.x = pack_bf16x2(v0.x, v0.y);
      o.y = pack_bf16x2(v0.z, v0.w);
      o.z = pack_bf16x2(v1.x, v1.y);
      o.w = pack_bf16x2(v1.z, v1.w);
      xb4[p] = o;
    }
  } else {
    for (long i = (long)(b - 2048) * 256 + tid; i < 2097152; i += 131072) {
      const int w = (int)(i >> 2);
      const int q = (int)(i & 3);
      const unsigned n = nz[w] >> (8 * q);
      const unsigned s = sgn[w] >> (8 * q);
      unsigned out[4];
#pragma unroll
      for (int pq = 0; pq < 4; ++pq) {
        const int j0 = 2 * pq, j1 = 2 * pq + 1;
        unsigned lo = ((n >> j0) & 1u) ? (0x3F80u | (((s >> j0) & 1u) << 15)) : 0u;
        unsigned hi = ((n >> j1) & 1u) ? (0x3F80u | (((s >> j1) & 1u) << 15)) : 0u;
        out[pq] = lo | (hi << 16);
      }
      uvec4 v = { out[0], out[1], out[2], out[3] };
      *(uvec4*)(wb + (long)w * 32 + q * 8) = v;
    }
  }
}

// ---- phase 2: bf16 GEMM, 256x256, BK=64, 8-wave, HYBRID single-barrier ------
// v5 = v4 + PROLOGUE RACE FIX (R7 post-mortem). v4's prologue did
// [vmcnt(4); reads] with NO barrier between: vmcnt is PER-WAVE, so wave W1
// could read tile-0 LDS before W2's cooperative global_load_lds writes
// landed (absmax 79). Fix: vmcnt(4); s_barrier; reads — now matching every
// other read-after-vmcnt site (EVM4/EVM0 = vmcnt, barrier, reads).
// Full audit (re-walked with per-wave drain semantics explicit):
//  - every read-after-stage site: vmcnt precedes a barrier that precedes reads;
//  - every STAGE into region R: issued after a barrier reachable only by waves
//    that executed the lgkmcnt(0) draining their last reads of R;
//  - vmcnt ledger: steady state 6 loads in flight, S4/S8 vmcnt(4) drains
//    exactly the next-consumed tile; prologue 12-issued/vmcnt(4) drains tile0.
// Schedule: segment = [barrier; lgkm0; setprio1; MFMA(p); setprio0;
// reads(p+1); stage]; extra barrier only at S4/S8 (EVM4) and epilogue (EVM0).
// MFMA order/numerics identical to R4.
__global__ __launch_bounds__(512, 2) void gemm_kernel(const unsigned short* __restrict__ A,
                                                      const unsigned short* __restrict__ B,
                                                      const float* __restrict__ bias,
                                                      const float* __restrict__ alpha,
                                                      float* __restrict__ C) {
  __shared__ unsigned short lds[65536];   // 128 KiB: A [buf][half] then B

  const int tid  = threadIdx.x;
  const int lane = tid & 63;
  const int wave = tid >> 6;        // 8 waves: 2(M) x 4(N)
  const int wm   = wave >> 2;       // M offset wm*128
  const int wn   = wave & 3;        // N offset wn*64

  // XCD-aware bijective swizzle (nwg = 512, divisible by 8)
  const int wg   = blockIdx.x;
  const int swz  = (wg & 7) * 64 + (wg >> 3);
  const int nBlk = (swz & 15) * 256;
  const int mBlk = (swz >> 4) * 256;

  const unsigned short* Apan = A + (long)mBlk * K_DIM;
  const unsigned short* Bpan = B + (long)nBlk * K_DIM;

  // staging map: half-tile = 128x64 bf16 = 16 KiB = 1024 chunks of 16 B.
  // LDS dest linear (m104); SOURCE carries the inverse swizzle (rule 21).
  int lOff[2], gOff[2];
#pragma unroll
  for (int l = 0; l < 2; ++l) {
    const int o = (l * 512 + tid) * 16;           // LDS byte offset in half slot
    const int r = o >> 7;                         // row (128 B per row)
    const int q = ((o >> 4) & 7) ^ (r & 7);       // global chunk (inverse swz)
    lOff[l] = o;
    gOff[l] = r * K_DIM + q * 8;                  // shorts
  }

  // fragment addressing (verified lane mapping)
  const int fr  = lane & 15;                      // row within 16-frag
  const int fq  = lane >> 4;                      // k-quad
  const int sl0 = fq ^ (fr & 7);                  // chunk slot kh=0 (kh=1: ^4)
  const int aFB = fr * 64;                        // shorts
  const int bFB = (wn & 1) * 4096 + fr * 64;
  const int A0S = wm * 8192;                      // A buf0, half wm
  const int A1S = (2 + wm) * 8192;                // A buf1, half wm
  const int B0S = 32768 + (wn >> 1) * 8192;       // B buf0, half wn>>1
  const int B1S = 32768 + (2 + (wn >> 1)) * 8192; // B buf1, half wn>>1

  f32x4  acc[8][4] = {};
  bf16x8 a[2][2], bv[4][2];

#define STAGE(SUBv, BUFv, TILEv) do {                                          \
    const unsigned short* s_ = (((SUBv) < 2) ? Apan : Bpan)                    \
        + (long)((SUBv) & 1) * (128 * K_DIM) + (long)(TILEv) * 64;             \
    const int dB = ((((SUBv) < 2) ? 0 : 32768)                                 \
        + (((BUFv) * 2) + ((SUBv) & 1)) * 8192) * 2;                           \
    __builtin_amdgcn_global_load_lds(                                          \
        (const __attribute__((address_space(1))) void*)(s_ + gOff[0]),         \
        (__attribute__((address_space(3))) void*)((char*)lds + dB + lOff[0]),  \
        16, 0, 0);                                                             \
    __builtin_amdgcn_global_load_lds(                                          \
        (const __attribute__((address_space(1))) void*)(s_ + gOff[1]),         \
        (__attribute__((address_space(3))) void*)((char*)lds + dB + lOff[1]),  \
        16, 0, 0);                                                             \
  } while (0)

// a-frags for M-row-pair P (rows 32P..32P+31 of wave's A-half): 4 ds_read_b128
#define LOADA2(BASE, P)                                                        \
  _Pragma("unroll")                                                            \
  for (int i = 0; i < 2; ++i) {                                                \
    const int off_ = (BASE) + ((P) * 2 + i) * 1024 + aFB;                      \
    a[i][0] = *(const bf16x8*)(lds + off_ + sl0 * 8);                          \
    a[i][1] = *(const bf16x8*)(lds + off_ + (sl0 ^ 4) * 8);                    \
  }

// all 4 B frags of wave's half: 8 ds_read_b128 (only before p1/p5)
#define LOADB(BASE)                                                            \
  _Pragma("unroll")                                                            \
  for (int j = 0; j < 4; ++j) {                                                \
    const int off_ = (BASE) + bFB + j * 1024;                                  \
    bv[j][0] = *(const bf16x8*)(lds + off_ + sl0 * 8);                         \
    bv[j][1] = *(const bf16x8*)(lds + off_ + (sl0 ^ 4) * 8);                   \
  }

// 16 MFMA: M-row-pair P x all 4 N x both kh
#define MFMA2(P)                                                               \
  _Pragma("unroll")                                                            \
  for (int kh = 0; kh < 2; ++kh)                                               \
    _Pragma("unroll")                                                          \
    for (int i = 0; i < 2; ++i)                                                \
      _Pragma("unroll")                                                        \
      for (int tn = 0; tn < 4; ++tn)                                           \
        acc[(P) * 2 + i][tn] = __builtin_amdgcn_mfma_f32_16x16x32_bf16(        \
            a[i][kh], bv[tn][kh], acc[(P) * 2 + i][tn], 0, 0, 0);

// segment head: barrier, drain this wave's pending ds_reads, boost prio
#define SEGH() __builtin_amdgcn_s_barrier();                                   \
               asm volatile("s_waitcnt lgkmcnt(0)" ::: "memory");              \
               __builtin_amdgcn_s_setprio(1)
#define PLO()  __builtin_amdgcn_s_setprio(0)
// E-barrier at vmcnt phases: landed-tile guarantee + gap-1 stage protection
#define EVM4() __builtin_amdgcn_s_setprio(0);                                  \
               asm volatile("s_waitcnt vmcnt(4)" ::: "memory");                \
               __builtin_amdgcn_s_barrier()
#define EVM0() __builtin_amdgcn_s_setprio(0);                                  \
               asm volatile("s_waitcnt vmcnt(0)" ::: "memory");                \
               __builtin_amdgcn_s_barrier()

  // ---- prologue: tile0 {B0,B1,A0,A1} + tile1 {B0,B1} ----
  STAGE(2, 0, 0); STAGE(3, 0, 0); STAGE(0, 0, 0); STAGE(1, 0, 0);
  STAGE(2, 1, 1); STAGE(3, 1, 1);
  asm volatile("s_waitcnt vmcnt(4)" ::: "memory");   // own tile-0 loads landed
  __builtin_amdgcn_s_barrier();                      // R7 FIX: ALL waves' tile-0
                                                     // loads landed (vmcnt is
                                                     // per-wave; reads below
                                                     // consume other waves' data)
  LOADA2(A0S, 0); LOADB(B0S);                        // reads(p1), tile 0
  STAGE(1, 1, 1);                                    // A1(1): in-flight = 6

  // ---- main loop: 31 iterations, computing tiles 0..61 ----
  for (int it = 0; it < (K_DIM / 64) / 2 - 1; ++it) {
    const int t1 = 2 * it + 1, t2 = 2 * it + 2, t3 = 2 * it + 3;
    // S1..S4: tile 2it (buf0)
    SEGH(); MFMA2(0); PLO(); LOADA2(A0S, 1); STAGE(0, 1, t1);   // A0(T+1)
    SEGH(); MFMA2(1); PLO(); LOADA2(A0S, 2); STAGE(2, 0, t2);   // B0(T+2)
    SEGH(); MFMA2(2); PLO(); LOADA2(A0S, 3); STAGE(3, 0, t2);   // B1(T+2)
    SEGH(); MFMA2(3); EVM4();                                   // tile T+1 landed
    LOADA2(A1S, 0); LOADB(B1S); STAGE(0, 0, t2);                // reads(p5); A0(T+2)
    // S5..S8: tile 2it+1 (buf1)
    SEGH(); MFMA2(0); PLO(); LOADA2(A1S, 1); STAGE(1, 0, t2);   // A1(T+2)
    SEGH(); MFMA2(1); PLO(); LOADA2(A1S, 2); STAGE(2, 1, t3);   // B0(T+3)
    SEGH(); MFMA2(2); PLO(); LOADA2(A1S, 3); STAGE(3, 1, t3);   // B1(T+3)
    SEGH(); MFMA2(3); EVM4();                                   // tile T+2 landed
    LOADA2(A0S, 0); LOADB(B0S); STAGE(1, 1, t3);                // reads(p1'); A1(T+3)
  }

  // ---- epilogue: tile 62 (buf0) + tile 63 (buf1); only A0(63) left to stage
  SEGH(); MFMA2(0); PLO(); LOADA2(A0S, 1); STAGE(0, 1, 63);
  SEGH(); MFMA2(1); PLO(); LOADA2(A0S, 2);
  SEGH(); MFMA2(2); PLO(); LOADA2(A0S, 3);
  SEGH(); MFMA2(3); EVM0();                                     // tile 63 landed
  LOADA2(A1S, 0); LOADB(B1S);
  SEGH(); MFMA2(0); PLO(); LOADA2(A1S, 1);
  SEGH(); MFMA2(1); PLO(); LOADA2(A1S, 2);
  SEGH(); MFMA2(2); PLO(); LOADA2(A1S, 3);
  SEGH(); MFMA2(3);
  __builtin_amdgcn_s_setprio(0);

  // ---- C write: C[m][n] = acc * alpha[n] + bias[n] (nontemporal, write-once)
  // C/D layout (verified m89/m91): col = lane&15, row = (lane>>4)*4 + reg
#pragma unroll
  for (int tn = 0; tn < 4; ++tn) {
    const int n = nBlk + wn * 64 + tn * 16 + fr;
    const float al = alpha[n];
    const float bi = bias[n];
#pragma unroll
    for (int tm = 0; tm < 8; ++tm) {
      const int mBase = mBlk + wm * 128 + tm * 16 + fq * 4;
#pragma unroll
      for (int r = 0; r < 4; ++r)
        __builtin_nontemporal_store(acc[tm][tn][r] * al + bi,
                                    C + (long)(mBase + r) * O_DIM + n);
    }
  }

#undef STAGE
#undef LOADA2
#undef LOADB
#undef MFMA2
#undef SEGH
#undef PLO
#undef EVM4
#undef EVM0
}

// ---- fallback (ws too small): slow but correct fp32 path --------------------
__global__ __launch_bounds__(256) void fallback_kernel(const float* __restrict__ x,
                                                       const unsigned* __restrict__ nz,
                                                       const unsigned* __restrict__ sgn,
                                                       const float* __restrict__ bias,
                                                       const float* __restrict__ alpha,
                                                       float* __restrict__ y) {
  long gid = (long)blockIdx.x * 256 + threadIdx.x;
  int o = (int)(gid % O_DIM);
  long m = gid / O_DIM;
  const float* xr = x + m * K_DIM;
  float s = 0.f;
  for (int w = 0; w < NWORDS; ++w) {
    unsigned n = nz[o * NWORDS + w];
    unsigned g = sgn[o * NWORDS + w];
    for (int j = 0; j < 32; ++j) {
      if ((n >> j) & 1u) {
        float v = xr[w * 32 + j];
        s += ((g >> j) & 1u) ? -v : v;
      }
    }
  }
  y[gid] = s * alpha[o] + bias[o];
}

extern "C" void kernel_launch(void* const* d_in, const int* in_sizes, int n_in,
                              void* d_out, int out_size, void* d_ws, size_t ws_size,
                              hipStream_t stream) {
  const float*    x     = (const float*)d_in[0];
  const unsigned* nz    = (const unsigned*)d_in[1];
  const unsigned* sgn   = (const unsigned*)d_in[2];
  const float*    bias  = (const float*)d_in[3];
  const float*    alpha = (const float*)d_in[4];
  float*          y     = (float*)d_out;

  const size_t xb_bytes = (size_t)M_DIM * K_DIM * 2;   // 64 MiB
  const size_t wb_bytes = (size_t)O_DIM * K_DIM * 2;   // 32 MiB

  if (ws_size >= xb_bytes + wb_bytes) {
    unsigned short* xb = (unsigned short*)d_ws;
    unsigned short* wb = (unsigned short*)((char*)d_ws + xb_bytes);

    prep_kernel<<<2560, 256, 0, stream>>>((const fvec4*)x, (uvec4*)xb, nz, sgn, wb);
    gemm_kernel<<<512, 512, 0, stream>>>(xb, wb, bias, alpha, y);
  } else {
    fallback_kernel<<<(long)M_DIM * O_DIM / 256, 256, 0, stream>>>(x, nz, sgn, bias, alpha, y);
  }
}